// Round 10
// baseline (166.554 us; speedup 1.0000x reference)
//
#include <hip/hip_runtime.h>

constexpr int NODES = 50000;
constexpr int EDGES = 600000;
constexpr int DIM = 128;
constexpr int CHUNK = 1024;                            // scan chunk
constexpr int NB_SCAN = (NODES + CHUNK - 1) / CHUNK;   // 49
constexpr int HBINS = 8192;                            // bins per range (32KB LDS each)
constexpr int HRANGES = (NODES + HBINS - 1) / HBINS;   // 7
constexpr int HC = 40;                                 // edge chunks
constexpr int EPC = EDGES / HC;                        // 15000
constexpr int EPC4 = EPC / 4;                          // 3750
constexpr int TW_BLOCKS = DIM * DIM / 256;             // 64 transpose blocks

typedef __attribute__((ext_vector_type(8))) short short8v;
typedef __attribute__((ext_vector_type(8))) unsigned short ushort8v;
typedef __attribute__((ext_vector_type(4))) float f32x4;

__device__ __forceinline__ unsigned short f2bf(float f) {
    unsigned int b = __float_as_uint(f);
    b += 0x7fffu + ((b >> 16) & 1u);                   // round-to-nearest-even
    return (unsigned short)(b >> 16);
}

// swizzled LDS byte offset: row stride 256B (128 bf16), 16B slot XOR row&7
__device__ __forceinline__ int swz(int row, int oct) {
    return row * 256 + ((oct ^ (row & 7)) << 4);
}

// ---------- Stage 1: W-transpose (blocks 0..63) + fused src/dst histograms --
// hist block (r,c): both src and dst chunk c filtered to range r, 64KB LDS.
__global__ __launch_bounds__(256) void prep_kernel(const float* __restrict__ W,
                                                   const int* __restrict__ src,
                                                   const int* __restrict__ dst,
                                                   unsigned short* __restrict__ Wt,
                                                   unsigned short* __restrict__ partial,
                                                   int* __restrict__ scan_part) {
    __shared__ int hs[HBINS];
    __shared__ int hd[HBINS];
    int b = blockIdx.x;
    int tid = threadIdx.x;
    if (b < TW_BLOCKS) {
        int t = b * 256 + tid;
        int n = t >> 7, k = t & 127;
        Wt[t] = f2bf(W[k * DIM + n]);
        if (b == 0 && tid < 64) scan_part[tid] = 0;
        return;
    }
    b -= TW_BLOCKS;
    int r = b / HC, c = b % HC;
    for (int i = tid; i < HBINS; i += 256) { hs[i] = 0; hd[i] = 0; }
    __syncthreads();
    const int4* s4 = reinterpret_cast<const int4*>(src);
    const int4* d4 = reinterpret_cast<const int4*>(dst);
    int t0 = c * EPC4;
    int base = r * HBINS;
    for (int t = t0 + tid; t < t0 + EPC4; t += 256) {
        int4 v = s4[t];
        int a;
        a = v.x - base; if ((unsigned)a < (unsigned)HBINS) atomicAdd(&hs[a], 1);
        a = v.y - base; if ((unsigned)a < (unsigned)HBINS) atomicAdd(&hs[a], 1);
        a = v.z - base; if ((unsigned)a < (unsigned)HBINS) atomicAdd(&hs[a], 1);
        a = v.w - base; if ((unsigned)a < (unsigned)HBINS) atomicAdd(&hs[a], 1);
        int4 w = d4[t];
        a = w.x - base; if ((unsigned)a < (unsigned)HBINS) atomicAdd(&hd[a], 1);
        a = w.y - base; if ((unsigned)a < (unsigned)HBINS) atomicAdd(&hd[a], 1);
        a = w.z - base; if ((unsigned)a < (unsigned)HBINS) atomicAdd(&hd[a], 1);
        a = w.w - base; if ((unsigned)a < (unsigned)HBINS) atomicAdd(&hd[a], 1);
    }
    __syncthreads();
    unsigned short* ops = partial + (size_t)(r * HC + c) * HBINS;
    unsigned short* opd = ops + (size_t)HRANGES * HC * HBINS;
    for (int i = tid; i < HBINS; i += 256) {
        ops[i] = (unsigned short)hs[i];
        opd[i] = (unsigned short)hd[i];
    }
}

// ---------- Stage 2: fused degree-reduce + chunk offsets + scan partials ----
__global__ __launch_bounds__(256) void deg_coff(const unsigned short* __restrict__ partial,
                                                int* __restrict__ deg_out,
                                                int* __restrict__ deg_in,
                                                unsigned short* __restrict__ cumoff,
                                                int* __restrict__ scan_part) {
    __shared__ int bsum[4];
    int tid = threadIdx.x;
    int n = blockIdx.x * 256 + tid;                    // over R*HBINS = 57344
    int r = n >> 13, bin = n & (HBINS - 1);
    const unsigned short* ps = partial;
    const unsigned short* pd = partial + (size_t)HRANGES * HC * HBINS;
    int s0 = 0, run = 0;
    #pragma unroll 8
    for (int c = 0; c < HC; ++c) {
        size_t idx = (size_t)(r * HC + c) * HBINS + bin;
        s0 += ps[idx];
        cumoff[idx] = (unsigned short)run;
        run += pd[idx];
    }
    if (n < NODES) {
        deg_out[n] = s0;
        deg_in[n] = run;
    }
    // block-local sum of in-degrees -> one atomic per block (4 blocks per
    // 1024-node scan chunk)
    int lane = tid & 63, wid = tid >> 6;
    int v = (n < NODES) ? run : 0;
    #pragma unroll
    for (int off = 32; off; off >>= 1) v += __shfl_down(v, off, 64);
    if (lane == 0) bsum[wid] = v;
    __syncthreads();
    if (tid == 0)
        atomicAdd(&scan_part[blockIdx.x >> 2], bsum[0] + bsum[1] + bsum[2] + bsum[3]);
}

// ---------- Stage 3: chunk-local exclusive scan + global offset ----------
__global__ __launch_bounds__(256) void scan_chunks(const int* __restrict__ deg_in,
                                                   const int* __restrict__ scan_part,
                                                   int* __restrict__ row_start) {
    __shared__ int wsum[4];
    __shared__ int blockoff_s;
    int b = blockIdx.x, tid = threadIdx.x, lane = tid & 63, wid = tid >> 6;
    if (wid == 0) {
        int v = (lane < b) ? scan_part[lane] : 0;      // NB_SCAN=49 <= 64
        #pragma unroll
        for (int off = 32; off; off >>= 1) v += __shfl_down(v, off, 64);
        if (lane == 0) blockoff_s = v;
    }
    int base = b * CHUNK + tid * 4;
    int v[4];
    int s = 0;
    #pragma unroll
    for (int i = 0; i < 4; ++i) {
        v[i] = (base + i < NODES) ? deg_in[base + i] : 0;
        s += v[i];
    }
    int incl = s;
    #pragma unroll
    for (int off = 1; off < 64; off <<= 1) {
        int t = __shfl_up(incl, off, 64);
        if (lane >= off) incl += t;
    }
    if (lane == 63) wsum[wid] = incl;
    __syncthreads();
    int wbase = 0;
    for (int w = 0; w < wid; ++w) wbase += wsum[w];
    int run = blockoff_s + wbase + incl - s;
    #pragma unroll
    for (int i = 0; i < 4; ++i) {
        if (base + i < NODES) row_start[base + i] = run;
        run += v[i];
    }
}

// ---------- Stage 4: bucket edges by dst via LDS cursors ----------
__global__ __launch_bounds__(256) void bucket_lds(const int* __restrict__ src,
                                                  const int* __restrict__ dst,
                                                  const int* __restrict__ row_start,
                                                  const unsigned short* __restrict__ cumoff,
                                                  int* __restrict__ csr_src) {
    __shared__ int cur[HBINS];
    int r = blockIdx.x / HC, c = blockIdx.x % HC;
    int tid = threadIdx.x;
    int base = r * HBINS;
    const unsigned short* co = cumoff + (size_t)(r * HC + c) * HBINS;
    for (int i = tid; i < HBINS; i += 256) {
        int n = base + i;
        int rs = (n < NODES) ? row_start[n] : 0;
        cur[i] = rs + (int)co[i];
    }
    __syncthreads();
    const int4* dst4 = reinterpret_cast<const int4*>(dst);
    const int4* src4 = reinterpret_cast<const int4*>(src);
    int t0 = c * EPC4;
    for (int t = t0 + tid; t < t0 + EPC4; t += 256) {
        int4 dv = dst4[t];
        int4 sv = src4[t];
        int d;
        d = dv.x - base; if ((unsigned)d < (unsigned)HBINS) csr_src[atomicAdd(&cur[d], 1)] = sv.x;
        d = dv.y - base; if ((unsigned)d < (unsigned)HBINS) csr_src[atomicAdd(&cur[d], 1)] = sv.y;
        d = dv.z - base; if ((unsigned)d < (unsigned)HBINS) csr_src[atomicAdd(&cur[d], 1)] = sv.z;
        d = dv.w - base; if ((unsigned)d < (unsigned)HBINS) csr_src[atomicAdd(&cur[d], 1)] = sv.w;
    }
}

// ---------- Stage 5: H = bf16((X * rsqrt(out_deg)) @ W) via MFMA ----------
__global__ __launch_bounds__(256) void gemm_mfma(const float* __restrict__ X,
                                                 const int* __restrict__ deg_out,
                                                 const unsigned short* __restrict__ Wt,
                                                 unsigned short* __restrict__ H) {
    __shared__ char XsB[64 * 256];    // 64 rows x 128 bf16, swizzled (16KB)
    __shared__ char WsB[128 * 256];   // Wt[n][k] bf16, swizzled (32KB)
    int tid = threadIdx.x;
    int row0 = blockIdx.x * 64;

    for (int t = tid; t < 128 * 16; t += 256) {
        int n = t >> 4, o = t & 15;
        ushort8v wv = *reinterpret_cast<const ushort8v*>(Wt + n * DIM + o * 8);
        *reinterpret_cast<ushort8v*>(WsB + swz(n, o)) = wv;
    }
    for (int t = tid; t < 64 * 16; t += 256) {
        int r = t >> 4, o = t & 15;
        int node = row0 + r;
        float4 v0 = make_float4(0.f, 0.f, 0.f, 0.f), v1 = v0;
        float sc = 0.f;
        if (node < NODES) {
            const float4* rp = reinterpret_cast<const float4*>(X + (size_t)node * DIM);
            v0 = rp[o * 2];
            v1 = rp[o * 2 + 1];
            int dg = deg_out[node];
            sc = rsqrtf((float)(dg > 0 ? dg : 1));
        }
        ushort8v h;
        h[0] = f2bf(v0.x * sc); h[1] = f2bf(v0.y * sc);
        h[2] = f2bf(v0.z * sc); h[3] = f2bf(v0.w * sc);
        h[4] = f2bf(v1.x * sc); h[5] = f2bf(v1.y * sc);
        h[6] = f2bf(v1.z * sc); h[7] = f2bf(v1.w * sc);
        *reinterpret_cast<ushort8v*>(XsB + swz(r, o)) = h;
    }
    __syncthreads();

    int w = tid >> 6, l = tid & 63;
    int lr = l & 15, lg = l >> 4;
    f32x4 acc[8];
    #pragma unroll
    for (int nt = 0; nt < 8; ++nt) acc[nt] = (f32x4){0.f, 0.f, 0.f, 0.f};
    #pragma unroll
    for (int kb = 0; kb < 4; ++kb) {
        short8v a = *reinterpret_cast<short8v*>(XsB + swz(w * 16 + lr, kb * 4 + lg));
        #pragma unroll
        for (int nt = 0; nt < 8; ++nt) {
            short8v bfr = *reinterpret_cast<short8v*>(WsB + swz(nt * 16 + lr, kb * 4 + lg));
            acc[nt] = __builtin_amdgcn_mfma_f32_16x16x32_bf16(a, bfr, acc[nt], 0, 0, 0);
        }
    }
    #pragma unroll
    for (int nt = 0; nt < 8; ++nt) {
        int col = nt * 16 + lr;
        #pragma unroll
        for (int rg = 0; rg < 4; ++rg) {
            int m = w * 16 + lg * 4 + rg;
            int byte = m * 256 + (((col >> 3) ^ (m & 7)) << 4) + (col & 7) * 2;
            *reinterpret_cast<unsigned short*>(XsB + byte) = f2bf(acc[nt][rg]);
        }
    }
    __syncthreads();
    for (int t = tid; t < 64 * 16; t += 256) {
        int r = t >> 4, o = t & 15;
        int node = row0 + r;
        if (node < NODES)
            *reinterpret_cast<ushort8v*>(H + (size_t)node * DIM + o * 8) =
                *reinterpret_cast<ushort8v*>(XsB + swz(r, o));
    }
}

// ---------- Stage 6: out[n] = relu(rsqrt(in_deg)*sum H[src] + b) ----------
// One wave per node, TWO H-rows per iteration (half-wave each, uint2/lane),
// 4x-unrolled independent loads; cross-half shfl_xor(32) reduction at end.
__global__ __launch_bounds__(256) void gather_kernel(const uint2* __restrict__ H2,
                                                     const int* __restrict__ row_start,
                                                     const int* __restrict__ deg_in,
                                                     const int* __restrict__ csr_src,
                                                     const float* __restrict__ bias,
                                                     float* __restrict__ out) {
    int gw = (blockIdx.x * 256 + threadIdx.x) >> 6;
    int lane = threadIdx.x & 63;
    if (gw >= NODES) return;
    int half = lane >> 5;           // 0: even edges, 1: odd edges
    int sub = lane & 31;            // uint2 index within row (dims sub*4..+3)
    int start = row_start[gw];
    int deg = deg_in[gw];
    float ax = 0.f, ay = 0.f, az = 0.f, aw = 0.f;
    for (int i0 = 0; i0 < deg; i0 += 64) {
        int nv = min(64, deg - i0);
        int sv = 0;
        if (i0 + lane < deg) sv = csr_src[start + i0 + lane];
        int i = 0;
        for (; i + 8 <= nv; i += 8) {
            int s0 = __shfl(sv, i + half, 64);
            int s1 = __shfl(sv, i + 2 + half, 64);
            int s2 = __shfl(sv, i + 4 + half, 64);
            int s3 = __shfl(sv, i + 6 + half, 64);
            uint2 u0 = H2[(size_t)s0 * 32 + sub];
            uint2 u1 = H2[(size_t)s1 * 32 + sub];
            uint2 u2 = H2[(size_t)s2 * 32 + sub];
            uint2 u3 = H2[(size_t)s3 * 32 + sub];
            ax += __uint_as_float(u0.x << 16); ay += __uint_as_float(u0.x & 0xffff0000u);
            az += __uint_as_float(u0.y << 16); aw += __uint_as_float(u0.y & 0xffff0000u);
            ax += __uint_as_float(u1.x << 16); ay += __uint_as_float(u1.x & 0xffff0000u);
            az += __uint_as_float(u1.y << 16); aw += __uint_as_float(u1.y & 0xffff0000u);
            ax += __uint_as_float(u2.x << 16); ay += __uint_as_float(u2.x & 0xffff0000u);
            az += __uint_as_float(u2.y << 16); aw += __uint_as_float(u2.y & 0xffff0000u);
            ax += __uint_as_float(u3.x << 16); ay += __uint_as_float(u3.x & 0xffff0000u);
            az += __uint_as_float(u3.y << 16); aw += __uint_as_float(u3.y & 0xffff0000u);
        }
        for (; i + 2 <= nv; i += 2) {
            int s = __shfl(sv, i + half, 64);
            uint2 u = H2[(size_t)s * 32 + sub];
            ax += __uint_as_float(u.x << 16); ay += __uint_as_float(u.x & 0xffff0000u);
            az += __uint_as_float(u.y << 16); aw += __uint_as_float(u.y & 0xffff0000u);
        }
        if (i < nv) {                       // odd remainder: half 0 only
            int s = __shfl(sv, i, 64);
            if (half == 0) {
                uint2 u = H2[(size_t)s * 32 + sub];
                ax += __uint_as_float(u.x << 16); ay += __uint_as_float(u.x & 0xffff0000u);
                az += __uint_as_float(u.y << 16); aw += __uint_as_float(u.y & 0xffff0000u);
            }
        }
    }
    ax += __shfl_xor(ax, 32, 64);
    ay += __shfl_xor(ay, 32, 64);
    az += __shfl_xor(az, 32, 64);
    aw += __shfl_xor(aw, 32, 64);
    if (half == 0) {
        float sc = rsqrtf((float)(deg > 0 ? deg : 1));
        float4 bb = reinterpret_cast<const float4*>(bias)[sub];
        float4 o;
        o.x = fmaxf(ax * sc + bb.x, 0.f);
        o.y = fmaxf(ay * sc + bb.y, 0.f);
        o.z = fmaxf(az * sc + bb.z, 0.f);
        o.w = fmaxf(aw * sc + bb.w, 0.f);
        reinterpret_cast<float4*>(out)[(size_t)gw * 32 + sub] = o;
    }
}

extern "C" void kernel_launch(void* const* d_in, const int* in_sizes, int n_in,
                              void* d_out, int out_size, void* d_ws, size_t ws_size,
                              hipStream_t stream) {
    const float* feat = (const float*)d_in[0];
    const float* W    = (const float*)d_in[1];
    const float* b    = (const float*)d_in[2];
    const int*   src  = (const int*)d_in[3];
    const int*   dst  = (const int*)d_in[4];
    float* out = (float*)d_out;

    constexpr size_t PART_ELEMS = (size_t)HRANGES * HC * HBINS;   // 2,293,760

    char* p = (char*)d_ws;
    // Region A: partial_src | partial_dst | cumoff (3x PART ushort = 13.76MB).
    // H (12.8MB) aliases this region — partial/cumoff are dead before gemm_mfma.
    unsigned short* partial = (unsigned short*)p;
    unsigned short* cumoff  = partial + 2 * PART_ELEMS;
    unsigned short* H       = (unsigned short*)p;
    p += 3 * PART_ELEMS * sizeof(unsigned short);
    unsigned short* Wt = (unsigned short*)p;  p += (size_t)DIM * DIM * 2;
    int* deg_out   = (int*)p;  p += (size_t)NODES * 4;
    int* deg_in    = (int*)p;  p += (size_t)NODES * 4;
    int* row_start = (int*)p;  p += (size_t)NODES * 4;
    int* scan_part = (int*)p;  p += 256;
    int* csr_src   = (int*)p;                                     // 2.4MB

    prep_kernel<<<TW_BLOCKS + HRANGES * HC, 256, 0, stream>>>(W, src, dst, Wt, partial, scan_part);
    deg_coff<<<(HRANGES * HBINS) / 256, 256, 0, stream>>>(partial, deg_out, deg_in, cumoff, scan_part);
    scan_chunks<<<NB_SCAN, 256, 0, stream>>>(deg_in, scan_part, row_start);
    bucket_lds<<<HRANGES * HC, 256, 0, stream>>>(src, dst, row_start, cumoff, csr_src);
    gemm_mfma<<<(NODES + 63) / 64, 256, 0, stream>>>(feat, deg_out, Wt, H);
    gather_kernel<<<(NODES * 64 + 255) / 256, 256, 0, stream>>>(
        (const uint2*)H, row_start, deg_in, csr_src, b, out);
}

// Round 13
// 155.368 us; speedup vs baseline: 1.0720x; 1.0720x over previous
//
#include <hip/hip_runtime.h>

constexpr int NODES = 50000;
constexpr int EDGES = 600000;
constexpr int DIM = 128;
constexpr int CHUNK = 1024;                            // scan chunk
constexpr int NB_SCAN = (NODES + CHUNK - 1) / CHUNK;   // 49
constexpr int HB = 32768;                              // bins per range (packed ushort, 64KB LDS)
constexpr int HB2 = HB / 2;                            // uints per LDS array
constexpr int NR = 2;                                  // ranges (2*32768 >= 50000)
constexpr int HCS = 40;                                // src-hist chunks
constexpr int EPCS4 = EDGES / HCS / 4;                 // 3750
constexpr int HCD = 80;                                // dst-hist / bucket chunks
constexpr int EPCD4 = EDGES / HCD / 4;                 // 1875
constexpr int TW_BLOCKS = DIM * DIM / 256;             // 64 transpose blocks

typedef __attribute__((ext_vector_type(8))) short short8v;
typedef __attribute__((ext_vector_type(8))) unsigned short ushort8v;
typedef __attribute__((ext_vector_type(4))) float f32x4;

__device__ __forceinline__ unsigned short f2bf(float f) {
    unsigned int b = __float_as_uint(f);
    b += 0x7fffu + ((b >> 16) & 1u);                   // round-to-nearest-even
    return (unsigned short)(b >> 16);
}

// swizzled LDS byte offset: row stride 256B (128 bf16), 16B slot XOR row&7
__device__ __forceinline__ int swz(int row, int oct) {
    return row * 256 + ((oct ^ (row & 7)) << 4);
}

// ---------- Stage 1: W-transpose + packed-ushort LDS histograms ----------
// blocks [0,64): Wt; [64,144): src hist (2r x 40c); [144,304): dst hist (2r x 80c)
__global__ __launch_bounds__(256) void prep_kernel(const float* __restrict__ W,
                                                   const int* __restrict__ src,
                                                   const int* __restrict__ dst,
                                                   unsigned short* __restrict__ Wt,
                                                   unsigned short* __restrict__ part_s,
                                                   unsigned short* __restrict__ part_d,
                                                   int* __restrict__ scan_part) {
    __shared__ unsigned int h[HB2];                    // 64KB: 32768 packed ushort bins
    int b = blockIdx.x, tid = threadIdx.x;
    if (b < TW_BLOCKS) {
        int t = b * 256 + tid;
        Wt[t] = f2bf(W[(t & 127) * DIM + (t >> 7)]);
        if (b == 0 && tid < 64) scan_part[tid] = 0;
        return;
    }
    b -= TW_BLOCKS;
    const int4* e4;
    int r, nb4, t0;
    unsigned short* outp;
    if (b < NR * HCS) {                                // src histogram
        r = b / HCS;
        e4 = reinterpret_cast<const int4*>(src);
        nb4 = EPCS4; t0 = (b % HCS) * EPCS4;
        outp = part_s + (size_t)b * HB;
    } else {                                           // dst histogram
        b -= NR * HCS;
        r = b / HCD;
        e4 = reinterpret_cast<const int4*>(dst);
        nb4 = EPCD4; t0 = (b % HCD) * EPCD4;
        outp = part_d + (size_t)b * HB;
    }
    for (int i = tid; i < HB2; i += 256) h[i] = 0;
    __syncthreads();
    int base = r * HB;
    for (int t = t0 + tid; t < t0 + nb4; t += 256) {
        int4 v = e4[t];
        int a;
        a = v.x - base; if ((unsigned)a < (unsigned)HB) atomicAdd(&h[a >> 1], 1u << (16 * (a & 1)));
        a = v.y - base; if ((unsigned)a < (unsigned)HB) atomicAdd(&h[a >> 1], 1u << (16 * (a & 1)));
        a = v.z - base; if ((unsigned)a < (unsigned)HB) atomicAdd(&h[a >> 1], 1u << (16 * (a & 1)));
        a = v.w - base; if ((unsigned)a < (unsigned)HB) atomicAdd(&h[a >> 1], 1u << (16 * (a & 1)));
    }
    __syncthreads();
    unsigned int* o32 = reinterpret_cast<unsigned int*>(outp);   // little-endian: low ushort = even bin
    for (int i = tid; i < HB2; i += 256) o32[i] = h[i];
}

// ---------- Stage 2: degree-reduce + per-chunk cumulative offsets + scan partials
__global__ __launch_bounds__(256) void deg_coff(const unsigned short* __restrict__ part_s,
                                                const unsigned short* __restrict__ part_d,
                                                int* __restrict__ deg_out,
                                                int* __restrict__ deg_in,
                                                unsigned short* __restrict__ cumoff,
                                                int* __restrict__ scan_part) {
    __shared__ int bsum[4];
    int tid = threadIdx.x;
    int n = blockIdx.x * 256 + tid;                    // over NR*HB = 65536
    int r = n >> 15, bin = n & (HB - 1);
    int s0 = 0;
    #pragma unroll 8
    for (int c = 0; c < HCS; ++c)
        s0 += part_s[(size_t)(r * HCS + c) * HB + bin];
    int run = 0;
    #pragma unroll 8
    for (int c = 0; c < HCD; ++c) {
        size_t idx = (size_t)(r * HCD + c) * HB + bin;
        cumoff[idx] = (unsigned short)run;
        run += part_d[idx];
    }
    if (n < NODES) {
        deg_out[n] = s0;
        deg_in[n] = run;
    }
    // block-local in-degree sum -> one atomic per block (4 blocks / 1024-chunk)
    int lane = tid & 63, wid = tid >> 6;
    int v = (n < NODES) ? run : 0;
    #pragma unroll
    for (int off = 32; off; off >>= 1) v += __shfl_down(v, off, 64);
    if (lane == 0) bsum[wid] = v;
    __syncthreads();
    if (tid == 0)
        atomicAdd(&scan_part[blockIdx.x >> 2], bsum[0] + bsum[1] + bsum[2] + bsum[3]);
}

// ---------- Stage 3: chunk-local exclusive scan + global offset ----------
__global__ __launch_bounds__(256) void scan_chunks(const int* __restrict__ deg_in,
                                                   const int* __restrict__ scan_part,
                                                   int* __restrict__ row_start) {
    __shared__ int wsum[4];
    __shared__ int blockoff_s;
    int b = blockIdx.x, tid = threadIdx.x, lane = tid & 63, wid = tid >> 6;
    if (wid == 0) {
        int v = (lane < b) ? scan_part[lane] : 0;      // NB_SCAN=49 <= 64
        #pragma unroll
        for (int off = 32; off; off >>= 1) v += __shfl_down(v, off, 64);
        if (lane == 0) blockoff_s = v;
    }
    int base = b * CHUNK + tid * 4;
    int v[4];
    int s = 0;
    #pragma unroll
    for (int i = 0; i < 4; ++i) {
        v[i] = (base + i < NODES) ? deg_in[base + i] : 0;
        s += v[i];
    }
    int incl = s;
    #pragma unroll
    for (int off = 1; off < 64; off <<= 1) {
        int t = __shfl_up(incl, off, 64);
        if (lane >= off) incl += t;
    }
    if (lane == 63) wsum[wid] = incl;
    __syncthreads();
    int wbase = 0;
    for (int w = 0; w < wid; ++w) wbase += wsum[w];
    int run = blockoff_s + wbase + incl - s;
    #pragma unroll
    for (int i = 0; i < 4; ++i) {
        if (base + i < NODES) row_start[base + i] = run;
        run += v[i];
    }
}

// ---------- Stage 4: bucket via packed-ushort LDS cursors ----------
// cursor = offset relative to row_start[node]; pos = row_start[node] + off.
__global__ __launch_bounds__(256) void bucket_lds(const int* __restrict__ src,
                                                  const int* __restrict__ dst,
                                                  const int* __restrict__ row_start,
                                                  const unsigned short* __restrict__ cumoff,
                                                  int* __restrict__ csr_src) {
    __shared__ unsigned int cur[HB2];                  // 64KB packed cursors
    int b = blockIdx.x;
    int r = b / HCD, c = b % HCD;
    int tid = threadIdx.x;
    int base = r * HB;
    const unsigned int* co32 = reinterpret_cast<const unsigned int*>(cumoff + (size_t)b * HB);
    for (int i = tid; i < HB2; i += 256) cur[i] = co32[i];
    __syncthreads();
    const int4* d4 = reinterpret_cast<const int4*>(dst);
    const int4* s4 = reinterpret_cast<const int4*>(src);
    int t0 = c * EPCD4;
    for (int t = t0 + tid; t < t0 + EPCD4; t += 256) {
        int4 dv = d4[t];
        int4 sv = s4[t];
        int d;
        unsigned int old;
        d = dv.x - base;
        if ((unsigned)d < (unsigned)HB) {
            old = atomicAdd(&cur[d >> 1], 1u << (16 * (d & 1)));
            csr_src[row_start[base + d] + ((old >> (16 * (d & 1))) & 0xffff)] = sv.x;
        }
        d = dv.y - base;
        if ((unsigned)d < (unsigned)HB) {
            old = atomicAdd(&cur[d >> 1], 1u << (16 * (d & 1)));
            csr_src[row_start[base + d] + ((old >> (16 * (d & 1))) & 0xffff)] = sv.y;
        }
        d = dv.z - base;
        if ((unsigned)d < (unsigned)HB) {
            old = atomicAdd(&cur[d >> 1], 1u << (16 * (d & 1)));
            csr_src[row_start[base + d] + ((old >> (16 * (d & 1))) & 0xffff)] = sv.z;
        }
        d = dv.w - base;
        if ((unsigned)d < (unsigned)HB) {
            old = atomicAdd(&cur[d >> 1], 1u << (16 * (d & 1)));
            csr_src[row_start[base + d] + ((old >> (16 * (d & 1))) & 0xffff)] = sv.w;
        }
    }
}

// ---------- Stage 5: H = bf16((X * rsqrt(out_deg)) @ W) via MFMA ----------
__global__ __launch_bounds__(256) void gemm_mfma(const float* __restrict__ X,
                                                 const int* __restrict__ deg_out,
                                                 const unsigned short* __restrict__ Wt,
                                                 unsigned short* __restrict__ H) {
    __shared__ char XsB[64 * 256];    // 64 rows x 128 bf16, swizzled (16KB)
    __shared__ char WsB[128 * 256];   // Wt[n][k] bf16, swizzled (32KB)
    int tid = threadIdx.x;
    int row0 = blockIdx.x * 64;

    for (int t = tid; t < 128 * 16; t += 256) {
        int n = t >> 4, o = t & 15;
        ushort8v wv = *reinterpret_cast<const ushort8v*>(Wt + n * DIM + o * 8);
        *reinterpret_cast<ushort8v*>(WsB + swz(n, o)) = wv;
    }
    for (int t = tid; t < 64 * 16; t += 256) {
        int r = t >> 4, o = t & 15;
        int node = row0 + r;
        float4 v0 = make_float4(0.f, 0.f, 0.f, 0.f), v1 = v0;
        float sc = 0.f;
        if (node < NODES) {
            const float4* rp = reinterpret_cast<const float4*>(X + (size_t)node * DIM);
            v0 = rp[o * 2];
            v1 = rp[o * 2 + 1];
            int dg = deg_out[node];
            sc = rsqrtf((float)(dg > 0 ? dg : 1));
        }
        ushort8v h;
        h[0] = f2bf(v0.x * sc); h[1] = f2bf(v0.y * sc);
        h[2] = f2bf(v0.z * sc); h[3] = f2bf(v0.w * sc);
        h[4] = f2bf(v1.x * sc); h[5] = f2bf(v1.y * sc);
        h[6] = f2bf(v1.z * sc); h[7] = f2bf(v1.w * sc);
        *reinterpret_cast<ushort8v*>(XsB + swz(r, o)) = h;
    }
    __syncthreads();

    int w = tid >> 6, l = tid & 63;
    int lr = l & 15, lg = l >> 4;
    f32x4 acc[8];
    #pragma unroll
    for (int nt = 0; nt < 8; ++nt) acc[nt] = (f32x4){0.f, 0.f, 0.f, 0.f};
    #pragma unroll
    for (int kb = 0; kb < 4; ++kb) {
        short8v a = *reinterpret_cast<short8v*>(XsB + swz(w * 16 + lr, kb * 4 + lg));
        #pragma unroll
        for (int nt = 0; nt < 8; ++nt) {
            short8v bfr = *reinterpret_cast<short8v*>(WsB + swz(nt * 16 + lr, kb * 4 + lg));
            acc[nt] = __builtin_amdgcn_mfma_f32_16x16x32_bf16(a, bfr, acc[nt], 0, 0, 0);
        }
    }
    #pragma unroll
    for (int nt = 0; nt < 8; ++nt) {
        int col = nt * 16 + lr;
        #pragma unroll
        for (int rg = 0; rg < 4; ++rg) {
            int m = w * 16 + lg * 4 + rg;
            int byte = m * 256 + (((col >> 3) ^ (m & 7)) << 4) + (col & 7) * 2;
            *reinterpret_cast<unsigned short*>(XsB + byte) = f2bf(acc[nt][rg]);
        }
    }
    __syncthreads();
    for (int t = tid; t < 64 * 16; t += 256) {
        int r = t >> 4, o = t & 15;
        int node = row0 + r;
        if (node < NODES)
            *reinterpret_cast<ushort8v*>(H + (size_t)node * DIM + o * 8) =
                *reinterpret_cast<ushort8v*>(XsB + swz(r, o));
    }
}

// ---------- Stage 6: out[n] = relu(rsqrt(in_deg)*sum H[src] + b) ----------
// One wave per node, two H-rows per iteration (half-wave each, uint2/lane).
__global__ __launch_bounds__(256) void gather_kernel(const uint2* __restrict__ H2,
                                                     const int* __restrict__ row_start,
                                                     const int* __restrict__ deg_in,
                                                     const int* __restrict__ csr_src,
                                                     const float* __restrict__ bias,
                                                     float* __restrict__ out) {
    int gw = (blockIdx.x * 256 + threadIdx.x) >> 6;
    int lane = threadIdx.x & 63;
    if (gw >= NODES) return;
    int half = lane >> 5;
    int sub = lane & 31;
    int start = row_start[gw];
    int deg = deg_in[gw];
    float ax = 0.f, ay = 0.f, az = 0.f, aw = 0.f;
    for (int i0 = 0; i0 < deg; i0 += 64) {
        int nv = min(64, deg - i0);
        int sv = 0;
        if (i0 + lane < deg) sv = csr_src[start + i0 + lane];
        int i = 0;
        for (; i + 8 <= nv; i += 8) {
            int s0 = __shfl(sv, i + half, 64);
            int s1 = __shfl(sv, i + 2 + half, 64);
            int s2 = __shfl(sv, i + 4 + half, 64);
            int s3 = __shfl(sv, i + 6 + half, 64);
            uint2 u0 = H2[(size_t)s0 * 32 + sub];
            uint2 u1 = H2[(size_t)s1 * 32 + sub];
            uint2 u2 = H2[(size_t)s2 * 32 + sub];
            uint2 u3 = H2[(size_t)s3 * 32 + sub];
            ax += __uint_as_float(u0.x << 16); ay += __uint_as_float(u0.x & 0xffff0000u);
            az += __uint_as_float(u0.y << 16); aw += __uint_as_float(u0.y & 0xffff0000u);
            ax += __uint_as_float(u1.x << 16); ay += __uint_as_float(u1.x & 0xffff0000u);
            az += __uint_as_float(u1.y << 16); aw += __uint_as_float(u1.y & 0xffff0000u);
            ax += __uint_as_float(u2.x << 16); ay += __uint_as_float(u2.x & 0xffff0000u);
            az += __uint_as_float(u2.y << 16); aw += __uint_as_float(u2.y & 0xffff0000u);
            ax += __uint_as_float(u3.x << 16); ay += __uint_as_float(u3.x & 0xffff0000u);
            az += __uint_as_float(u3.y << 16); aw += __uint_as_float(u3.y & 0xffff0000u);
        }
        for (; i + 2 <= nv; i += 2) {
            int s = __shfl(sv, i + half, 64);
            uint2 u = H2[(size_t)s * 32 + sub];
            ax += __uint_as_float(u.x << 16); ay += __uint_as_float(u.x & 0xffff0000u);
            az += __uint_as_float(u.y << 16); aw += __uint_as_float(u.y & 0xffff0000u);
        }
        if (i < nv) {
            int s = __shfl(sv, i, 64);
            if (half == 0) {
                uint2 u = H2[(size_t)s * 32 + sub];
                ax += __uint_as_float(u.x << 16); ay += __uint_as_float(u.x & 0xffff0000u);
                az += __uint_as_float(u.y << 16); aw += __uint_as_float(u.y & 0xffff0000u);
            }
        }
    }
    ax += __shfl_xor(ax, 32, 64);
    ay += __shfl_xor(ay, 32, 64);
    az += __shfl_xor(az, 32, 64);
    aw += __shfl_xor(aw, 32, 64);
    if (half == 0) {
        float sc = rsqrtf((float)(deg > 0 ? deg : 1));
        float4 bb = reinterpret_cast<const float4*>(bias)[sub];
        float4 o;
        o.x = fmaxf(ax * sc + bb.x, 0.f);
        o.y = fmaxf(ay * sc + bb.y, 0.f);
        o.z = fmaxf(az * sc + bb.z, 0.f);
        o.w = fmaxf(aw * sc + bb.w, 0.f);
        reinterpret_cast<float4*>(out)[(size_t)gw * 32 + sub] = o;
    }
}

extern "C" void kernel_launch(void* const* d_in, const int* in_sizes, int n_in,
                              void* d_out, int out_size, void* d_ws, size_t ws_size,
                              hipStream_t stream) {
    const float* feat = (const float*)d_in[0];
    const float* W    = (const float*)d_in[1];
    const float* b    = (const float*)d_in[2];
    const int*   src  = (const int*)d_in[3];
    const int*   dst  = (const int*)d_in[4];
    float* out = (float*)d_out;

    constexpr size_t PART_S_ELEMS = (size_t)NR * HCS * HB;   // 2,621,440
    constexpr size_t PART_D_ELEMS = (size_t)NR * HCD * HB;   // 5,242,880

    char* p = (char*)d_ws;
    // Region A: part_s | part_d | cumoff (26.2MB total, ushort).
    // H (12.8MB) aliases part_s+part_d — both dead after deg_coff/bucket,
    // which complete before gemm_mfma writes H.
    unsigned short* part_s = (unsigned short*)p;
    unsigned short* part_d = part_s + PART_S_ELEMS;
    unsigned short* cumoff = part_d + PART_D_ELEMS;
    unsigned short* H      = (unsigned short*)p;
    p += (PART_S_ELEMS + 2 * PART_D_ELEMS) * sizeof(unsigned short);
    unsigned short* Wt = (unsigned short*)p;  p += (size_t)DIM * DIM * 2;
    int* deg_out   = (int*)p;  p += (size_t)NODES * 4;
    int* deg_in    = (int*)p;  p += (size_t)NODES * 4;
    int* row_start = (int*)p;  p += (size_t)NODES * 4;
    int* scan_part = (int*)p;  p += 256;
    int* csr_src   = (int*)p;                                // 2.4MB

    prep_kernel<<<TW_BLOCKS + NR * HCS + NR * HCD, 256, 0, stream>>>(
        W, src, dst, Wt, part_s, part_d, scan_part);
    deg_coff<<<(NR * HB) / 256, 256, 0, stream>>>(
        part_s, part_d, deg_out, deg_in, cumoff, scan_part);
    scan_chunks<<<NB_SCAN, 256, 0, stream>>>(deg_in, scan_part, row_start);
    bucket_lds<<<NR * HCD, 256, 0, stream>>>(src, dst, row_start, cumoff, csr_src);
    gemm_mfma<<<(NODES + 63) / 64, 256, 0, stream>>>(feat, deg_out, Wt, H);
    gather_kernel<<<(NODES * 64 + 255) / 256, 256, 0, stream>>>(
        (const uint2*)H, row_start, deg_in, csr_src, b, out);
}